// Round 1
// baseline (221.313 us; speedup 1.0000x reference)
//
#include <hip/hip_runtime.h>
#include <math.h>

#define NPTS 4096
#define EPSV 1e-5f

// Stable top-3 insert (ascending-m scan, strict > keeps earlier index on ties,
// matching lax.top_k's stable ordering).
__device__ __forceinline__ void top3_insert(float d, int m,
                                            float& d0, float& d1, float& d2,
                                            int& i0, int& i1, int& i2) {
  if (d > d2) {
    bool g1 = d > d1;
    bool g0 = d > d0;
    d2 = g1 ? d1 : d;                 i2 = g1 ? i1 : m;
    d1 = g0 ? d0 : (g1 ? d : d1);     i1 = g0 ? i0 : (g1 ? m : i1);
    d0 = g0 ? d : d0;                 i0 = g0 ? m : i0;
  }
}

// ---------------------------------------------------------------------------
// K1: stage-1 KNN. Points are the flat-view columns P_n = (buf[n], buf[4096+n],
// buf[8192+n]). dist = 2*dot - |p|^2 - |q|^2 (self-distance exactly 0 since the
// fma chains for dot and |.|^2 are identical). 128 points x 4 scanners per
// block (chunk=1024), merge in LDS with exact (d desc, idx asc) ordering.
// ---------------------------------------------------------------------------
__global__ __launch_bounds__(512) void k_knn1(const float* __restrict__ x,
                                              int* __restrict__ idx1) {
  __shared__ float4 pts[NPTS];           // 64 KB: x,y,z,|x|^2
  __shared__ float cd[128][4][3];
  __shared__ int   ci[128][4][3];
  const int b   = blockIdx.x >> 5;       // 32 blocks per batch
  const int blk = blockIdx.x & 31;
  const float* xb = x + b * (NPTS * 3);
  const int t = threadIdx.x;

  for (int m = t; m < NPTS; m += 512) {
    float a0 = xb[m], a1 = xb[NPTS + m], a2 = xb[2 * NPTS + m];
    float xx = a0 * a0; xx = fmaf(a1, a1, xx); xx = fmaf(a2, a2, xx);
    pts[m] = make_float4(a0, a1, a2, xx);
  }
  __syncthreads();

  const int p = t & 127;                 // point within block
  const int s = t >> 7;                  // scanner id (wave-uniform)
  const int n = blk * 128 + p;
  const float4 pn = pts[n];
  const float c0 = -pn.w;
  float d0 = -INFINITY, d1 = -INFINITY, d2 = -INFINITY;
  int   i0 = 0x7fffffff, i1 = 0x7fffffff, i2 = 0x7fffffff;
  const int mstart = s * 1024;
  for (int m = mstart; m < mstart + 1024; ++m) {
    float4 q = pts[m];
    float dot = pn.x * q.x; dot = fmaf(pn.y, q.y, dot); dot = fmaf(pn.z, q.z, dot);
    float d = fmaf(2.0f, dot, c0) - q.w;
    top3_insert(d, m, d0, d1, d2, i0, i1, i2);
  }
  cd[p][s][0] = d0; cd[p][s][1] = d1; cd[p][s][2] = d2;
  ci[p][s][0] = i0; ci[p][s][1] = i1; ci[p][s][2] = i2;
  __syncthreads();

  if (t < 128) {
    int* op = idx1 + (b * NPTS + blk * 128 + t) * 3;
    float pd = INFINITY; int pi = -1;    // previously selected (none yet)
    for (int r = 0; r < 3; ++r) {
      float bd = -INFINITY; int bi = 0x7fffffff;
      for (int sc = 0; sc < 4; ++sc) {
        for (int kk = 0; kk < 3; ++kk) {
          float dv = cd[t][sc][kk]; int iv = ci[t][sc][kk];
          bool allowed = (dv < pd) || (dv == pd && iv > pi);
          bool better  = (dv > bd) || (dv == bd && iv < bi);
          if (allowed && better) { bd = dv; bi = iv; }
        }
      }
      op[r] = bi;
      pd = bd; pi = bi;
    }
  }
}

// ---------------------------------------------------------------------------
// K2: h[b,o,k,n] = sum_c w1[o,c] * F(c,k,n), partial max over n-tiles.
// F(c,k,n): ofs = c*12288 + k*4096 + n ; n'=ofs/18, k'=(ofs%18)/6, c'=ofs%6;
//   c'<3 : x[j*3+c'] - x[n'*3+c'] with j = idx1[n'][k'] ; else x[n'*3+c'-3].
// Grid 8*3*16 blocks; phase A: 256 F-vectors to LDS; phase B: lane o keeps
// w1-row in regs, maxes over 64 n, writes partial to workspace.
// ---------------------------------------------------------------------------
__global__ __launch_bounds__(256) void k_convmax(const float* __restrict__ x,
                                                 const int* __restrict__ idx1,
                                                 const float* __restrict__ w1,
                                                 float* __restrict__ pmax) {
  __shared__ float Ft[256][8];           // padded row (32B) for b128 reads
  __shared__ float w1s[384];
  const int b    = blockIdx.x / 48;
  const int rr   = blockIdx.x - b * 48;
  const int kk   = rr >> 4;
  const int tile = rr & 15;
  const int t = threadIdx.x;
  for (int i = t; i < 384; i += 256) w1s[i] = w1[i];
  const float* xb = x + b * 12288;
  const int*   ib = idx1 + b * 12288;
  const int n = tile * 256 + t;
#pragma unroll
  for (int c = 0; c < 6; ++c) {
    int ofs = c * 12288 + kk * 4096 + n;
    int np  = ofs / 18;
    int rem = ofs - np * 18;
    int kp  = rem / 6;
    int cp  = rem - kp * 6;
    float val;
    if (cp < 3) {
      int j = ib[np * 3 + kp];
      val = xb[j * 3 + cp] - xb[np * 3 + cp];
    } else {
      val = xb[np * 3 + cp - 3];
    }
    Ft[t][c] = val;
  }
  __syncthreads();
  const int o = t & 63, sub = t >> 6;
  float w[6];
#pragma unroll
  for (int c = 0; c < 6; ++c) w[c] = w1s[o * 6 + c];
  float mx = -INFINITY;
  const int base = sub * 64;
  for (int i = 0; i < 64; ++i) {
    const float* f = Ft[base + i];
    float h = w[0] * f[0];
    h = fmaf(w[1], f[1], h);
    h = fmaf(w[2], f[2], h);
    h = fmaf(w[3], f[3], h);
    h = fmaf(w[4], f[4], h);
    h = fmaf(w[5], f[5], h);
    mx = fmaxf(mx, h);
  }
  pmax[((b * 3 + kk) * 64 + (tile * 4 + sub)) * 64 + o] = mx;
}

// ---------------------------------------------------------------------------
// K3: per-batch tail. Reduce partials -> bn1+leaky -> x1 (64,3); graph-feature
// stages 2..4 (N=64 then 6,6; same ofs/18 decode); p[82]; MLP A/B/C; softmax.
// ---------------------------------------------------------------------------
__global__ __launch_bounds__(256) void k_tail(
    const float* __restrict__ pmax,
    const float* __restrict__ bn1g, const float* __restrict__ bn1b,
    const float* __restrict__ bn1m, const float* __restrict__ bn1v,
    const float* __restrict__ wA, const float* __restrict__ bA,
    const float* __restrict__ bnAg, const float* __restrict__ bnAb,
    const float* __restrict__ bnAm, const float* __restrict__ bnAv,
    const float* __restrict__ wB, const float* __restrict__ bB,
    const float* __restrict__ bnBg, const float* __restrict__ bnBb,
    const float* __restrict__ bnBm, const float* __restrict__ bnBv,
    const float* __restrict__ wC, const float* __restrict__ bC,
    float* __restrict__ out) {
  __shared__ float a1[192];
  __shared__ int   idx2[192];
  __shared__ float a2[18], a3[18], a4[18];
  __shared__ int   idxs[18];
  __shared__ float pv[82];
  __shared__ float hA[256];
  __shared__ float hB[128];
  __shared__ float lg[3];
  const int b = blockIdx.x;
  const int t = threadIdx.x;

  // step 1: x1[o][k] = leaky(bn1(max over 64 subtiles))  (bn monotone: g>0)
  if (t < 192) {
    int o = t / 3, k = t - o * 3;
    const float* pp = pmax + (b * 3 + k) * 4096 + o;
    float mx = -INFINITY;
    for (int st = 0; st < 64; ++st) mx = fmaxf(mx, pp[st * 64]);
    float inv = bn1g[o] / sqrtf(bn1v[o] + EPSV);
    float v = (mx - bn1m[o]) * inv + bn1b[o];
    a1[o * 3 + k] = v >= 0.f ? v : 0.2f * v;
  }
  __syncthreads();

  // step 2: KNN over 64 points, P_n = (a1[n], a1[64+n], a1[128+n])
  if (t < 64) {
    float px = a1[t], py = a1[64 + t], pz = a1[128 + t];
    float pp = px * px; pp = fmaf(py, py, pp); pp = fmaf(pz, pz, pp);
    float d0 = -INFINITY, d1 = -INFINITY, d2 = -INFINITY;
    int i0 = 0, i1 = 0, i2 = 0;
    for (int m = 0; m < 64; ++m) {
      float qx = a1[m], qy = a1[64 + m], qz = a1[128 + m];
      float qq = qx * qx; qq = fmaf(qy, qy, qq); qq = fmaf(qz, qz, qq);
      float dot = px * qx; dot = fmaf(py, qy, dot); dot = fmaf(pz, qz, dot);
      float d = 2.f * dot - pp - qq;
      top3_insert(d, m, d0, d1, d2, i0, i1, i2);
    }
    idx2[t * 3 + 0] = i0; idx2[t * 3 + 1] = i1; idx2[t * 3 + 2] = i2;
  }
  __syncthreads();

  // step 3: x2[o][kk] = max_nn F2(ofs = o*192 + kk*64 + nn)
  if (t < 18) {
    int o = t / 3, kk = t - o * 3;
    float mx = -INFINITY;
    for (int nn = 0; nn < 64; ++nn) {
      int ofs = o * 192 + kk * 64 + nn;
      int np = ofs / 18; int rem = ofs - np * 18;
      int kp = rem / 6;  int cp  = rem - kp * 6;
      float val = (cp < 3) ? (a1[idx2[np * 3 + kp] * 3 + cp] - a1[np * 3 + cp])
                           : a1[np * 3 + cp - 3];
      mx = fmaxf(mx, val);
    }
    a2[t] = mx;
  }
  __syncthreads();

  // steps 4-5: N=6 graph-feature twice (a2 -> a3 -> a4)
  for (int stage = 0; stage < 2; ++stage) {
    const float* src = (stage == 0) ? a2 : a3;
    float*       dst = (stage == 0) ? a3 : a4;
    if (t < 6) {
      float px = src[t], py = src[6 + t], pz = src[12 + t];
      float pp = px * px; pp = fmaf(py, py, pp); pp = fmaf(pz, pz, pp);
      float d0 = -INFINITY, d1 = -INFINITY, d2 = -INFINITY;
      int i0 = 0, i1 = 0, i2 = 0;
      for (int m = 0; m < 6; ++m) {
        float qx = src[m], qy = src[6 + m], qz = src[12 + m];
        float qq = qx * qx; qq = fmaf(qy, qy, qq); qq = fmaf(qz, qz, qq);
        float dot = px * qx; dot = fmaf(py, qy, dot); dot = fmaf(pz, qz, dot);
        float d = 2.f * dot - pp - qq;
        top3_insert(d, m, d0, d1, d2, i0, i1, i2);
      }
      idxs[t * 3 + 0] = i0; idxs[t * 3 + 1] = i1; idxs[t * 3 + 2] = i2;
    }
    __syncthreads();
    if (t < 18) {
      int o = t / 3, kk = t - o * 3;
      float mx = -INFINITY;
      for (int nn = 0; nn < 6; ++nn) {
        int ofs = o * 18 + kk * 6 + nn;
        int np = ofs / 18; int rem = ofs - np * 18;
        int kp = rem / 6;  int cp  = rem - kp * 6;
        float val = (cp < 3) ? (src[idxs[np * 3 + kp] * 3 + cp] - src[np * 3 + cp])
                             : src[np * 3 + cp - 3];
        mx = fmaxf(mx, val);
      }
      dst[t] = mx;
    }
    __syncthreads();
  }

  // step 6: p[82] = max over k
  if (t < 82) {
    float mx;
    if (t < 64)      { int o = t;      mx = fmaxf(fmaxf(a1[o*3], a1[o*3+1]), a1[o*3+2]); }
    else if (t < 70) { int o = t - 64; mx = fmaxf(fmaxf(a2[o*3], a2[o*3+1]), a2[o*3+2]); }
    else if (t < 76) { int o = t - 70; mx = fmaxf(fmaxf(a3[o*3], a3[o*3+1]), a3[o*3+2]); }
    else             { int o = t - 76; mx = fmaxf(fmaxf(a4[o*3], a4[o*3+1]), a4[o*3+2]); }
    pv[t] = mx;
  }
  __syncthreads();

  // step 7: hA = leaky(bnA(p @ wA.T + bA))  (256 outputs)
  {
    float acc = bA[t];
    const float* wr = wA + t * 82;
    for (int i = 0; i < 82; ++i) acc = fmaf(wr[i], pv[i], acc);
    float inv = bnAg[t] / sqrtf(bnAv[t] + EPSV);
    float v = (acc - bnAm[t]) * inv + bnAb[t];
    hA[t] = v >= 0.f ? v : 0.2f * v;
  }
  __syncthreads();

  // step 8: hB (128 outputs)
  if (t < 128) {
    float acc = bB[t];
    const float* wr = wB + t * 256;
    for (int i = 0; i < 256; ++i) acc = fmaf(wr[i], hA[i], acc);
    float inv = bnBg[t] / sqrtf(bnBv[t] + EPSV);
    float v = (acc - bnBm[t]) * inv + bnBb[t];
    hB[t] = v >= 0.f ? v : 0.2f * v;
  }
  __syncthreads();

  // step 9: logits + softmax
  if (t < 3) {
    float acc = bC[t];
    const float* wr = wC + t * 128;
    for (int i = 0; i < 128; ++i) acc = fmaf(wr[i], hB[i], acc);
    lg[t] = acc;
  }
  __syncthreads();
  if (t == 0) {
    float m = fmaxf(fmaxf(lg[0], lg[1]), lg[2]);
    float e0 = expf(lg[0] - m), e1 = expf(lg[1] - m), e2 = expf(lg[2] - m);
    float s = e0 + e1 + e2;
    out[b * 3 + 0] = e0 / s;
    out[b * 3 + 1] = e1 / s;
    out[b * 3 + 2] = e2 / s;
  }
}

extern "C" void kernel_launch(void* const* d_in, const int* in_sizes, int n_in,
                              void* d_out, int out_size, void* d_ws, size_t ws_size,
                              hipStream_t stream) {
  (void)in_sizes; (void)n_in; (void)out_size; (void)ws_size;
  const float* x    = (const float*)d_in[0];
  const float* w1   = (const float*)d_in[1];
  const float* wA   = (const float*)d_in[2];
  const float* bA   = (const float*)d_in[3];
  const float* wB   = (const float*)d_in[4];
  const float* bB   = (const float*)d_in[5];
  const float* wC   = (const float*)d_in[6];
  const float* bC   = (const float*)d_in[7];
  const float* bn1g = (const float*)d_in[8];
  const float* bn1b = (const float*)d_in[9];
  const float* bn1m = (const float*)d_in[10];
  const float* bn1v = (const float*)d_in[11];
  const float* bnAg = (const float*)d_in[12];
  const float* bnAb = (const float*)d_in[13];
  const float* bnAm = (const float*)d_in[14];
  const float* bnAv = (const float*)d_in[15];
  const float* bnBg = (const float*)d_in[16];
  const float* bnBb = (const float*)d_in[17];
  const float* bnBm = (const float*)d_in[18];
  const float* bnBv = (const float*)d_in[19];
  float* out = (float*)d_out;

  int*   idx1 = (int*)d_ws;                                  // 8*4096*3 ints
  float* pmax = (float*)((char*)d_ws + 8 * 4096 * 3 * 4);    // 8*3*64*64 floats

  k_knn1<<<256, 512, 0, stream>>>(x, idx1);
  k_convmax<<<384, 256, 0, stream>>>(x, idx1, w1, pmax);
  k_tail<<<8, 256, 0, stream>>>(pmax,
                                bn1g, bn1b, bn1m, bn1v,
                                wA, bA, bnAg, bnAb, bnAm, bnAv,
                                wB, bB, bnBg, bnBb, bnBm, bnBv,
                                wC, bC, out);
}

// Round 2
// 187.076 us; speedup vs baseline: 1.1830x; 1.1830x over previous
//
#include <hip/hip_runtime.h>
#include <math.h>

#define NPTS 4096
#define EPSV 1e-5f

// Stable top-3 insert (strict > keeps earlier index on ties, matching
// lax.top_k's stable ordering for an ascending-m scan).
__device__ __forceinline__ void top3_insert(float d, int m,
                                            float& d0, float& d1, float& d2,
                                            int& i0, int& i1, int& i2) {
  if (d > d2) {
    bool g1 = d > d1;
    bool g0 = d > d0;
    d2 = g1 ? d1 : d;                 i2 = g1 ? i1 : m;
    d1 = g0 ? d0 : (g1 ? d : d1);     i1 = g0 ? i0 : (g1 ? m : i1);
    d0 = g0 ? d : d0;                 i0 = g0 ? m : i0;
  }
}

// ---------------------------------------------------------------------------
// K1: stage-1 KNN. Points are the flat-view columns P_n = (buf[n], buf[4096+n],
// buf[8192+n]). dist = 2*dot - |p|^2 - |q|^2 with identical fma chains for dot
// and |.|^2 so self-distance is exactly 0. 128 points x 4 scanners per block.
// Inner loop: register ping-pong double-buffer of 8 float4s so the broadcast
// ds_read_b128 latency is hidden (R1 showed ~100 cyc/iter = serialized).
// ---------------------------------------------------------------------------
__global__ __launch_bounds__(512) void k_knn1(const float* __restrict__ x,
                                              int* __restrict__ idx1) {
  __shared__ float4 pts[NPTS];           // 64 KB: x,y,z,|x|^2
  __shared__ float cd[128][4][3];
  __shared__ int   ci[128][4][3];
  const int b   = blockIdx.x >> 5;       // 32 blocks per batch
  const int blk = blockIdx.x & 31;
  const float* xb = x + b * (NPTS * 3);
  const int t = threadIdx.x;

  for (int m = t; m < NPTS; m += 512) {
    float a0 = xb[m], a1 = xb[NPTS + m], a2 = xb[2 * NPTS + m];
    float xx = a0 * a0; xx = fmaf(a1, a1, xx); xx = fmaf(a2, a2, xx);
    pts[m] = make_float4(a0, a1, a2, xx);
  }
  __syncthreads();

  const int p = t & 127;                 // point within block
  const int s = t >> 7;                  // scanner id (wave-uniform)
  const int n = blk * 128 + p;
  const float4 pn = pts[n];
  const float c0 = -pn.w;
  float d0 = -INFINITY, d1 = -INFINITY, d2 = -INFINITY;
  int   i0 = 0x7fffffff, i1 = 0x7fffffff, i2 = 0x7fffffff;
  const int mstart = s * 1024;

  float4 qa[8];
#pragma unroll
  for (int j = 0; j < 8; ++j) qa[j] = pts[mstart + j];

  for (int mb = 0; mb < 1024; mb += 16) {
    float4 qb[8];
#pragma unroll
    for (int j = 0; j < 8; ++j) qb[j] = pts[mstart + mb + 8 + j];
#pragma unroll
    for (int j = 0; j < 8; ++j) {
      float4 q = qa[j];
      float dot = pn.x * q.x; dot = fmaf(pn.y, q.y, dot); dot = fmaf(pn.z, q.z, dot);
      float d = fmaf(2.0f, dot, c0) - q.w;
      top3_insert(d, mstart + mb + j, d0, d1, d2, i0, i1, i2);
    }
#pragma unroll
    for (int j = 0; j < 8; ++j) qa[j] = pts[mstart + ((mb + 16 + j) & 1023)];
#pragma unroll
    for (int j = 0; j < 8; ++j) {
      float4 q = qb[j];
      float dot = pn.x * q.x; dot = fmaf(pn.y, q.y, dot); dot = fmaf(pn.z, q.z, dot);
      float d = fmaf(2.0f, dot, c0) - q.w;
      top3_insert(d, mstart + mb + 8 + j, d0, d1, d2, i0, i1, i2);
    }
  }

  cd[p][s][0] = d0; cd[p][s][1] = d1; cd[p][s][2] = d2;
  ci[p][s][0] = i0; ci[p][s][1] = i1; ci[p][s][2] = i2;
  __syncthreads();

  if (t < 128) {
    int* op = idx1 + (b * NPTS + blk * 128 + t) * 3;
    float pd = INFINITY; int pi = -1;    // previously selected (none yet)
    for (int r = 0; r < 3; ++r) {
      float bd = -INFINITY; int bi = 0x7fffffff;
      for (int sc = 0; sc < 4; ++sc) {
        for (int kk = 0; kk < 3; ++kk) {
          float dv = cd[t][sc][kk]; int iv = ci[t][sc][kk];
          bool allowed = (dv < pd) || (dv == pd && iv > pi);
          bool better  = (dv > bd) || (dv == bd && iv < bi);
          if (allowed && better) { bd = dv; bi = iv; }
        }
      }
      op[r] = bi;
      pd = bd; pi = bi;
    }
  }
}

// ---------------------------------------------------------------------------
// K2: h[b,o,k,n] = sum_c w1[o,c] * F(c,k,n), partial max over n.
// F(c,k,n): ofs = c*12288 + k*4096 + n ; n'=ofs/18, k'=(ofs%18)/6, c'=ofs%6;
//   c'<3 : x[j*3+c'] - x[n'*3+c'] with j = idx1[n'][k'] ; else x[n'*3+c'-3].
// Grid 8*3*32 blocks (tile = 128 n). Phase A: 2 threads per n each compute 3
// features into an LDS float4-pair row. Phase B: lane o keeps its w1-row in
// regs, 4 subs x 32 n with ping-pong float4 prefetch; block-reduce subs and
// write pmax transposed: pmax[((b*3+kk)*64+o)*32 + tile].
// ---------------------------------------------------------------------------
__global__ __launch_bounds__(256) void k_convmax(const float* __restrict__ x,
                                                 const int* __restrict__ idx1,
                                                 const float* __restrict__ w1,
                                                 float* __restrict__ pmax) {
  __shared__ float4 Ft4[128][2];         // row: f0..f3 | f4,f5,--,--
  __shared__ float w1s[384];
  __shared__ float smax[4][64];
  const int b    = blockIdx.x / 96;      // 96 = 3*32 blocks per batch
  const int rr   = blockIdx.x - b * 96;
  const int kk   = rr >> 5;
  const int tile = rr & 31;
  const int t = threadIdx.x;
  for (int i = t; i < 384; i += 256) w1s[i] = w1[i];
  const float* xb = x + b * 12288;
  const int*   ib = idx1 + b * 12288;

  const int tn = t & 127, ch = t >> 7;   // 2 threads per n, 3 channels each
  const int n = tile * 128 + tn;
  float* ftrow = (float*)&Ft4[tn][0];
#pragma unroll
  for (int j = 0; j < 3; ++j) {
    int c = ch * 3 + j;
    int ofs = c * 12288 + kk * 4096 + n;
    int np  = ofs / 18;
    int rem = ofs - np * 18;
    int kp  = rem / 6;
    int cp  = rem - kp * 6;
    float val;
    if (cp < 3) {
      int jj = ib[np * 3 + kp];
      val = xb[jj * 3 + cp] - xb[np * 3 + cp];
    } else {
      val = xb[np * 3 + cp - 3];
    }
    ftrow[c] = val;
  }
  __syncthreads();

  const int o = t & 63, sub = t >> 6;
  float w[6];
#pragma unroll
  for (int c = 0; c < 6; ++c) w[c] = w1s[o * 6 + c];
  const int base = sub * 32;
  float mx = -INFINITY;

  float4 ra[4][2];
#pragma unroll
  for (int r = 0; r < 4; ++r) { ra[r][0] = Ft4[base + r][0]; ra[r][1] = Ft4[base + r][1]; }

  for (int i = 0; i < 32; i += 8) {
    float4 rb[4][2];
#pragma unroll
    for (int r = 0; r < 4; ++r) {
      rb[r][0] = Ft4[base + i + 4 + r][0];
      rb[r][1] = Ft4[base + i + 4 + r][1];
    }
#pragma unroll
    for (int r = 0; r < 4; ++r) {
      float h = w[0] * ra[r][0].x;
      h = fmaf(w[1], ra[r][0].y, h);
      h = fmaf(w[2], ra[r][0].z, h);
      h = fmaf(w[3], ra[r][0].w, h);
      h = fmaf(w[4], ra[r][1].x, h);
      h = fmaf(w[5], ra[r][1].y, h);
      mx = fmaxf(mx, h);
    }
#pragma unroll
    for (int r = 0; r < 4; ++r) {
      int nr = base + ((i + 8 + r) & 31);
      ra[r][0] = Ft4[nr][0]; ra[r][1] = Ft4[nr][1];
    }
#pragma unroll
    for (int r = 0; r < 4; ++r) {
      float h = w[0] * rb[r][0].x;
      h = fmaf(w[1], rb[r][0].y, h);
      h = fmaf(w[2], rb[r][0].z, h);
      h = fmaf(w[3], rb[r][0].w, h);
      h = fmaf(w[4], rb[r][1].x, h);
      h = fmaf(w[5], rb[r][1].y, h);
      mx = fmaxf(mx, h);
    }
  }
  smax[sub][o] = mx;
  __syncthreads();
  if (t < 64) {
    float m01 = fmaxf(smax[0][t], smax[1][t]);
    float m23 = fmaxf(smax[2][t], smax[3][t]);
    pmax[((b * 3 + kk) * 64 + t) * 32 + tile] = fmaxf(m01, m23);
  }
}

// ---------------------------------------------------------------------------
// K3: per-batch tail. Reduce partials -> bn1+leaky -> x1 (64,3); graph-feature
// stages 2..4 (N=64 then 6,6; same ofs/18 decode); p[82]; MLP A/B/C; softmax.
// ---------------------------------------------------------------------------
__global__ __launch_bounds__(256) void k_tail(
    const float* __restrict__ pmax,
    const float* __restrict__ bn1g, const float* __restrict__ bn1b,
    const float* __restrict__ bn1m, const float* __restrict__ bn1v,
    const float* __restrict__ wA, const float* __restrict__ bA,
    const float* __restrict__ bnAg, const float* __restrict__ bnAb,
    const float* __restrict__ bnAm, const float* __restrict__ bnAv,
    const float* __restrict__ wB, const float* __restrict__ bB,
    const float* __restrict__ bnBg, const float* __restrict__ bnBb,
    const float* __restrict__ bnBm, const float* __restrict__ bnBv,
    const float* __restrict__ wC, const float* __restrict__ bC,
    float* __restrict__ out) {
  __shared__ float a1[192];
  __shared__ int   idx2[192];
  __shared__ float a2[18], a3[18], a4[18];
  __shared__ int   idxs[18];
  __shared__ float pv[82];
  __shared__ float hA[256];
  __shared__ float hB[128];
  __shared__ float lg[3];
  const int b = blockIdx.x;
  const int t = threadIdx.x;

  // step 1: x1[o][k] = leaky(bn1(max over 32 tiles))  (bn monotone: g>0)
  if (t < 192) {
    int o = t / 3, k = t - o * 3;
    const float4* p4 = (const float4*)(pmax + ((b * 3 + k) * 64 + o) * 32);
    float4 v[8];
#pragma unroll
    for (int j = 0; j < 8; ++j) v[j] = p4[j];
    float mx = -INFINITY;
#pragma unroll
    for (int j = 0; j < 8; ++j) {
      mx = fmaxf(mx, fmaxf(fmaxf(v[j].x, v[j].y), fmaxf(v[j].z, v[j].w)));
    }
    float inv = bn1g[o] / sqrtf(bn1v[o] + EPSV);
    float val = (mx - bn1m[o]) * inv + bn1b[o];
    a1[o * 3 + k] = val >= 0.f ? val : 0.2f * val;
  }
  __syncthreads();

  // step 2: KNN over 64 points, P_n = (a1[n], a1[64+n], a1[128+n])
  if (t < 64) {
    float px = a1[t], py = a1[64 + t], pz = a1[128 + t];
    float pp = px * px; pp = fmaf(py, py, pp); pp = fmaf(pz, pz, pp);
    float d0 = -INFINITY, d1 = -INFINITY, d2 = -INFINITY;
    int i0 = 0, i1 = 0, i2 = 0;
#pragma unroll 8
    for (int m = 0; m < 64; ++m) {
      float qx = a1[m], qy = a1[64 + m], qz = a1[128 + m];
      float qq = qx * qx; qq = fmaf(qy, qy, qq); qq = fmaf(qz, qz, qq);
      float dot = px * qx; dot = fmaf(py, qy, dot); dot = fmaf(pz, qz, dot);
      float d = 2.f * dot - pp - qq;
      top3_insert(d, m, d0, d1, d2, i0, i1, i2);
    }
    idx2[t * 3 + 0] = i0; idx2[t * 3 + 1] = i1; idx2[t * 3 + 2] = i2;
  }
  __syncthreads();

  // step 3: x2[o][kk] = max_nn F2(ofs = o*192 + kk*64 + nn)
  if (t < 18) {
    int o = t / 3, kk = t - o * 3;
    float mx = -INFINITY;
#pragma unroll 8
    for (int nn = 0; nn < 64; ++nn) {
      int ofs = o * 192 + kk * 64 + nn;
      int np = ofs / 18; int rem = ofs - np * 18;
      int kp = rem / 6;  int cp  = rem - kp * 6;
      float val = (cp < 3) ? (a1[idx2[np * 3 + kp] * 3 + cp] - a1[np * 3 + cp])
                           : a1[np * 3 + cp - 3];
      mx = fmaxf(mx, val);
    }
    a2[t] = mx;
  }
  __syncthreads();

  // steps 4-5: N=6 graph-feature twice (a2 -> a3 -> a4)
  for (int stage = 0; stage < 2; ++stage) {
    const float* src = (stage == 0) ? a2 : a3;
    float*       dst = (stage == 0) ? a3 : a4;
    if (t < 6) {
      float px = src[t], py = src[6 + t], pz = src[12 + t];
      float pp = px * px; pp = fmaf(py, py, pp); pp = fmaf(pz, pz, pp);
      float d0 = -INFINITY, d1 = -INFINITY, d2 = -INFINITY;
      int i0 = 0, i1 = 0, i2 = 0;
#pragma unroll
      for (int m = 0; m < 6; ++m) {
        float qx = src[m], qy = src[6 + m], qz = src[12 + m];
        float qq = qx * qx; qq = fmaf(qy, qy, qq); qq = fmaf(qz, qz, qq);
        float dot = px * qx; dot = fmaf(py, qy, dot); dot = fmaf(pz, qz, dot);
        float d = 2.f * dot - pp - qq;
        top3_insert(d, m, d0, d1, d2, i0, i1, i2);
      }
      idxs[t * 3 + 0] = i0; idxs[t * 3 + 1] = i1; idxs[t * 3 + 2] = i2;
    }
    __syncthreads();
    if (t < 18) {
      int o = t / 3, kk = t - o * 3;
      float mx = -INFINITY;
#pragma unroll
      for (int nn = 0; nn < 6; ++nn) {
        int ofs = o * 18 + kk * 6 + nn;
        int np = ofs / 18; int rem = ofs - np * 18;
        int kp = rem / 6;  int cp  = rem - kp * 6;
        float val = (cp < 3) ? (src[idxs[np * 3 + kp] * 3 + cp] - src[np * 3 + cp])
                             : src[np * 3 + cp - 3];
        mx = fmaxf(mx, val);
      }
      dst[t] = mx;
    }
    __syncthreads();
  }

  // step 6: p[82] = max over k
  if (t < 82) {
    float mx;
    if (t < 64)      { int o = t;      mx = fmaxf(fmaxf(a1[o*3], a1[o*3+1]), a1[o*3+2]); }
    else if (t < 70) { int o = t - 64; mx = fmaxf(fmaxf(a2[o*3], a2[o*3+1]), a2[o*3+2]); }
    else if (t < 76) { int o = t - 70; mx = fmaxf(fmaxf(a3[o*3], a3[o*3+1]), a3[o*3+2]); }
    else             { int o = t - 76; mx = fmaxf(fmaxf(a4[o*3], a4[o*3+1]), a4[o*3+2]); }
    pv[t] = mx;
  }
  __syncthreads();

  // step 7: hA = leaky(bnA(p @ wA.T + bA))  (256 outputs)
  {
    float acc = bA[t];
    const float* wr = wA + t * 82;
#pragma unroll 8
    for (int i = 0; i < 82; ++i) acc = fmaf(wr[i], pv[i], acc);
    float inv = bnAg[t] / sqrtf(bnAv[t] + EPSV);
    float v = (acc - bnAm[t]) * inv + bnAb[t];
    hA[t] = v >= 0.f ? v : 0.2f * v;
  }
  __syncthreads();

  // step 8: hB (128 outputs)
  if (t < 128) {
    float acc = bB[t];
    const float4* wr4 = (const float4*)(wB + t * 256);
#pragma unroll 8
    for (int i = 0; i < 64; ++i) {
      float4 wv = wr4[i];
      acc = fmaf(wv.x, hA[4 * i + 0], acc);
      acc = fmaf(wv.y, hA[4 * i + 1], acc);
      acc = fmaf(wv.z, hA[4 * i + 2], acc);
      acc = fmaf(wv.w, hA[4 * i + 3], acc);
    }
    float inv = bnBg[t] / sqrtf(bnBv[t] + EPSV);
    float v = (acc - bnBm[t]) * inv + bnBb[t];
    hB[t] = v >= 0.f ? v : 0.2f * v;
  }
  __syncthreads();

  // step 9: logits + softmax
  if (t < 3) {
    float acc = bC[t];
    const float* wr = wC + t * 128;
#pragma unroll 8
    for (int i = 0; i < 128; ++i) acc = fmaf(wr[i], hB[i], acc);
    lg[t] = acc;
  }
  __syncthreads();
  if (t == 0) {
    float m = fmaxf(fmaxf(lg[0], lg[1]), lg[2]);
    float e0 = expf(lg[0] - m), e1 = expf(lg[1] - m), e2 = expf(lg[2] - m);
    float s = e0 + e1 + e2;
    out[b * 3 + 0] = e0 / s;
    out[b * 3 + 1] = e1 / s;
    out[b * 3 + 2] = e2 / s;
  }
}

extern "C" void kernel_launch(void* const* d_in, const int* in_sizes, int n_in,
                              void* d_out, int out_size, void* d_ws, size_t ws_size,
                              hipStream_t stream) {
  (void)in_sizes; (void)n_in; (void)out_size; (void)ws_size;
  const float* x    = (const float*)d_in[0];
  const float* w1   = (const float*)d_in[1];
  const float* wA   = (const float*)d_in[2];
  const float* bA   = (const float*)d_in[3];
  const float* wB   = (const float*)d_in[4];
  const float* bB   = (const float*)d_in[5];
  const float* wC   = (const float*)d_in[6];
  const float* bC   = (const float*)d_in[7];
  const float* bn1g = (const float*)d_in[8];
  const float* bn1b = (const float*)d_in[9];
  const float* bn1m = (const float*)d_in[10];
  const float* bn1v = (const float*)d_in[11];
  const float* bnAg = (const float*)d_in[12];
  const float* bnAb = (const float*)d_in[13];
  const float* bnAm = (const float*)d_in[14];
  const float* bnAv = (const float*)d_in[15];
  const float* bnBg = (const float*)d_in[16];
  const float* bnBb = (const float*)d_in[17];
  const float* bnBm = (const float*)d_in[18];
  const float* bnBv = (const float*)d_in[19];
  float* out = (float*)d_out;

  int*   idx1 = (int*)d_ws;                                  // 8*4096*3 ints = 384 KB
  float* pmax = (float*)((char*)d_ws + 8 * 4096 * 3 * 4);    // 8*3*64*32 floats = 192 KB

  k_knn1<<<256, 512, 0, stream>>>(x, idx1);
  k_convmax<<<768, 256, 0, stream>>>(x, idx1, w1, pmax);
  k_tail<<<8, 256, 0, stream>>>(pmax,
                                bn1g, bn1b, bn1m, bn1v,
                                wA, bA, bnAg, bnAb, bnAm, bnAv,
                                wB, bB, bnBg, bnBb, bnBm, bnBv,
                                wC, bC, out);
}

// Round 3
// 181.628 us; speedup vs baseline: 1.2185x; 1.0300x over previous
//
#include <hip/hip_runtime.h>
#include <math.h>

#define NPTS 4096
#define EPSV 1e-5f

// ---------------------------------------------------------------------------
// K1: stage-1 KNN. Points are the flat-view columns P_n = (buf[n], buf[4096+n],
// buf[8192+n]). dist d = 2*p.q - |p|^2 - |q|^2 (all <= ~0; self wins by huge
// margin in random-normal data). 64 points x 8 scanners per block (chunk=512),
// register ping-pong prefetch of 8 float4s, RARE-BRANCH top-3 insert (most
// iterations: 5 VALU + s_cbranch_execz skip). Exact (d desc, idx asc) merge.
// ---------------------------------------------------------------------------
__global__ __launch_bounds__(512, 4) void k_knn1(const float* __restrict__ x,
                                                 int* __restrict__ idx1) {
  __shared__ float4 pts[NPTS];           // 64 KB: x,y,z,|x|^2
  __shared__ float cd[64][8][3];         // 6 KB
  __shared__ int   ci[64][8][3];         // 6 KB
  const int b   = blockIdx.x >> 6;       // 64 blocks per batch
  const int blk = blockIdx.x & 63;
  const float* xb = x + b * (NPTS * 3);
  const int t = threadIdx.x;

  for (int m = t; m < NPTS; m += 512) {
    float a0 = xb[m], a1 = xb[NPTS + m], a2 = xb[2 * NPTS + m];
    float xx = a0 * a0; xx = fmaf(a1, a1, xx); xx = fmaf(a2, a2, xx);
    pts[m] = make_float4(a0, a1, a2, xx);
  }
  __syncthreads();

  const int p = t & 63;                  // point within block
  const int s = t >> 6;                  // scanner id (wave-uniform)
  const int n = blk * 64 + p;
  const float4 pn = pts[n];
  const float p2x = 2.0f * pn.x, p2y = 2.0f * pn.y, p2z = 2.0f * pn.z;
  const float c0 = -pn.w;
  float d0 = -INFINITY, d1 = -INFINITY, d2 = -INFINITY;
  int   i0 = 0x7fffffff, i1 = 0x7fffffff, i2 = 0x7fffffff;
  const int mstart = s * 512;

  float4 qa[8];
#pragma unroll
  for (int j = 0; j < 8; ++j) qa[j] = pts[mstart + j];

  for (int mb = 0; mb < 512; mb += 16) {
    float4 qb[8];
#pragma unroll
    for (int j = 0; j < 8; ++j) qb[j] = pts[mstart + mb + 8 + j];
#pragma unroll
    for (int j = 0; j < 8; ++j) {
      float4 q = qa[j];
      float d = fmaf(p2x, q.x, fmaf(p2y, q.y, fmaf(p2z, q.z, c0))) - q.w;
      if (d > d2) {                      // rare after warm-up: real branch
        int m = mstart + mb + j;
        bool g1 = d > d1, g0 = d > d0;
        d2 = g1 ? d1 : d;               i2 = g1 ? i1 : m;
        d1 = g0 ? d0 : (g1 ? d : d1);   i1 = g0 ? i0 : (g1 ? m : i1);
        d0 = g0 ? d : d0;               i0 = g0 ? m : i0;
      }
    }
#pragma unroll
    for (int j = 0; j < 8; ++j) qa[j] = pts[mstart + ((mb + 16 + j) & 511)];
#pragma unroll
    for (int j = 0; j < 8; ++j) {
      float4 q = qb[j];
      float d = fmaf(p2x, q.x, fmaf(p2y, q.y, fmaf(p2z, q.z, c0))) - q.w;
      if (d > d2) {
        int m = mstart + mb + 8 + j;
        bool g1 = d > d1, g0 = d > d0;
        d2 = g1 ? d1 : d;               i2 = g1 ? i1 : m;
        d1 = g0 ? d0 : (g1 ? d : d1);   i1 = g0 ? i0 : (g1 ? m : i1);
        d0 = g0 ? d : d0;               i0 = g0 ? m : i0;
      }
    }
  }

  cd[p][s][0] = d0; cd[p][s][1] = d1; cd[p][s][2] = d2;
  ci[p][s][0] = i0; ci[p][s][1] = i1; ci[p][s][2] = i2;
  __syncthreads();

  if (t < 64) {
    int* op = idx1 + (b * NPTS + blk * 64 + t) * 3;
    float pd = INFINITY; int pi = -1;    // previously selected (none yet)
    for (int r = 0; r < 3; ++r) {
      float bd = -INFINITY; int bi = 0x7fffffff;
      for (int sc = 0; sc < 8; ++sc) {
        for (int kk = 0; kk < 3; ++kk) {
          float dv = cd[t][sc][kk]; int iv = ci[t][sc][kk];
          bool allowed = (dv < pd) || (dv == pd && iv > pi);
          bool better  = (dv > bd) || (dv == bd && iv < bi);
          if (allowed && better) { bd = dv; bi = iv; }
        }
      }
      op[r] = bi;
      pd = bd; pi = bi;
    }
  }
}

// ---------------------------------------------------------------------------
// K2: h[b,o,k,n] = sum_c w1[o,c] * F(c,k,n), partial max over n.
// F(c,k,n): ofs = c*12288 + k*4096 + n ; n'=ofs/18, k'=(ofs%18)/6, c'=ofs%6;
//   c'<3 : x[j*3+c'] - x[n'*3+c'] with j = idx1[n'][k'] ; else x[n'*3+c'-3].
// Per-batch x staged into LDS (48 KB) so the 9 gathers/thread hit LDS, not L2.
// Grid 8*3*32 blocks (tile = 128 n). Phase B: lane o keeps its w1-row in regs,
// 4 subs x 32 n with ping-pong float4 prefetch; block-reduce subs and write
// pmax transposed: pmax[((b*3+kk)*64+o)*32 + tile].
// ---------------------------------------------------------------------------
__global__ __launch_bounds__(256, 2) void k_convmax(const float* __restrict__ x,
                                                    const int* __restrict__ idx1,
                                                    const float* __restrict__ w1,
                                                    float* __restrict__ pmax) {
  __shared__ float  xs[12288];           // 48 KB per-batch x
  __shared__ float4 Ft4[128][2];         // row: f0..f3 | f4,f5,--,--
  __shared__ float  w1s[384];
  __shared__ float  smax[4][64];
  const int b    = blockIdx.x / 96;      // 96 = 3*32 blocks per batch
  const int rr   = blockIdx.x - b * 96;
  const int kk   = rr >> 5;
  const int tile = rr & 31;
  const int t = threadIdx.x;
  for (int i = t; i < 384; i += 256) w1s[i] = w1[i];
  {
    const float4* xb4 = (const float4*)(x + b * 12288);
    float4* xs4 = (float4*)xs;
#pragma unroll
    for (int i = 0; i < 12; ++i) xs4[t + 256 * i] = xb4[t + 256 * i];
  }
  const int* ib = idx1 + b * 12288;
  __syncthreads();

  const int tn = t & 127, ch = t >> 7;   // 2 threads per n, 3 channels each
  const int n = tile * 128 + tn;
  float* ftrow = (float*)&Ft4[tn][0];
#pragma unroll
  for (int j = 0; j < 3; ++j) {
    int c = ch * 3 + j;
    int ofs = c * 12288 + kk * 4096 + n;
    int np  = ofs / 18;
    int rem = ofs - np * 18;
    int kp  = rem / 6;
    int cp  = rem - kp * 6;
    float val;
    if (cp < 3) {
      int jj = ib[np * 3 + kp];
      val = xs[jj * 3 + cp] - xs[np * 3 + cp];
    } else {
      val = xs[np * 3 + cp - 3];
    }
    ftrow[c] = val;
  }
  __syncthreads();

  const int o = t & 63, sub = t >> 6;
  float w[6];
#pragma unroll
  for (int c = 0; c < 6; ++c) w[c] = w1s[o * 6 + c];
  const int base = sub * 32;
  float mx = -INFINITY;

  float4 ra[4][2];
#pragma unroll
  for (int r = 0; r < 4; ++r) { ra[r][0] = Ft4[base + r][0]; ra[r][1] = Ft4[base + r][1]; }

  for (int i = 0; i < 32; i += 8) {
    float4 rb[4][2];
#pragma unroll
    for (int r = 0; r < 4; ++r) {
      rb[r][0] = Ft4[base + i + 4 + r][0];
      rb[r][1] = Ft4[base + i + 4 + r][1];
    }
#pragma unroll
    for (int r = 0; r < 4; ++r) {
      float h = w[0] * ra[r][0].x;
      h = fmaf(w[1], ra[r][0].y, h);
      h = fmaf(w[2], ra[r][0].z, h);
      h = fmaf(w[3], ra[r][0].w, h);
      h = fmaf(w[4], ra[r][1].x, h);
      h = fmaf(w[5], ra[r][1].y, h);
      mx = fmaxf(mx, h);
    }
#pragma unroll
    for (int r = 0; r < 4; ++r) {
      int nr = base + ((i + 8 + r) & 31);
      ra[r][0] = Ft4[nr][0]; ra[r][1] = Ft4[nr][1];
    }
#pragma unroll
    for (int r = 0; r < 4; ++r) {
      float h = w[0] * rb[r][0].x;
      h = fmaf(w[1], rb[r][0].y, h);
      h = fmaf(w[2], rb[r][0].z, h);
      h = fmaf(w[3], rb[r][0].w, h);
      h = fmaf(w[4], rb[r][1].x, h);
      h = fmaf(w[5], rb[r][1].y, h);
      mx = fmaxf(mx, h);
    }
  }
  smax[sub][o] = mx;
  __syncthreads();
  if (t < 64) {
    float m01 = fmaxf(smax[0][t], smax[1][t]);
    float m23 = fmaxf(smax[2][t], smax[3][t]);
    pmax[((b * 3 + kk) * 64 + t) * 32 + tile] = fmaxf(m01, m23);
  }
}

// Stable top-3 insert for the tiny tail stages.
__device__ __forceinline__ void top3_insert(float d, int m,
                                            float& d0, float& d1, float& d2,
                                            int& i0, int& i1, int& i2) {
  if (d > d2) {
    bool g1 = d > d1;
    bool g0 = d > d0;
    d2 = g1 ? d1 : d;                 i2 = g1 ? i1 : m;
    d1 = g0 ? d0 : (g1 ? d : d1);     i1 = g0 ? i0 : (g1 ? m : i1);
    d0 = g0 ? d : d0;                 i0 = g0 ? m : i0;
  }
}

// ---------------------------------------------------------------------------
// K3: per-batch tail. Reduce partials -> bn1+leaky -> x1 (64,3); graph-feature
// stages 2..4 (N=64 then 6,6; same ofs/18 decode); p[82]; MLP A/B/C; softmax.
// ---------------------------------------------------------------------------
__global__ __launch_bounds__(256) void k_tail(
    const float* __restrict__ pmax,
    const float* __restrict__ bn1g, const float* __restrict__ bn1b,
    const float* __restrict__ bn1m, const float* __restrict__ bn1v,
    const float* __restrict__ wA, const float* __restrict__ bA,
    const float* __restrict__ bnAg, const float* __restrict__ bnAb,
    const float* __restrict__ bnAm, const float* __restrict__ bnAv,
    const float* __restrict__ wB, const float* __restrict__ bB,
    const float* __restrict__ bnBg, const float* __restrict__ bnBb,
    const float* __restrict__ bnBm, const float* __restrict__ bnBv,
    const float* __restrict__ wC, const float* __restrict__ bC,
    float* __restrict__ out) {
  __shared__ float a1[192];
  __shared__ int   idx2[192];
  __shared__ float a2[18], a3[18], a4[18];
  __shared__ int   idxs[18];
  __shared__ float pv[82];
  __shared__ float hA[256];
  __shared__ float hB[128];
  __shared__ float lg[3];
  const int b = blockIdx.x;
  const int t = threadIdx.x;

  // step 1: x1[o][k] = leaky(bn1(max over 32 tiles))  (bn monotone: g>0)
  if (t < 192) {
    int o = t / 3, k = t - o * 3;
    const float4* p4 = (const float4*)(pmax + ((b * 3 + k) * 64 + o) * 32);
    float4 v[8];
#pragma unroll
    for (int j = 0; j < 8; ++j) v[j] = p4[j];
    float mx = -INFINITY;
#pragma unroll
    for (int j = 0; j < 8; ++j) {
      mx = fmaxf(mx, fmaxf(fmaxf(v[j].x, v[j].y), fmaxf(v[j].z, v[j].w)));
    }
    float inv = bn1g[o] / sqrtf(bn1v[o] + EPSV);
    float val = (mx - bn1m[o]) * inv + bn1b[o];
    a1[o * 3 + k] = val >= 0.f ? val : 0.2f * val;
  }
  __syncthreads();

  // step 2: KNN over 64 points, P_n = (a1[n], a1[64+n], a1[128+n])
  if (t < 64) {
    float px = a1[t], py = a1[64 + t], pz = a1[128 + t];
    float pp = px * px; pp = fmaf(py, py, pp); pp = fmaf(pz, pz, pp);
    float d0 = -INFINITY, d1 = -INFINITY, d2 = -INFINITY;
    int i0 = 0, i1 = 0, i2 = 0;
#pragma unroll 8
    for (int m = 0; m < 64; ++m) {
      float qx = a1[m], qy = a1[64 + m], qz = a1[128 + m];
      float qq = qx * qx; qq = fmaf(qy, qy, qq); qq = fmaf(qz, qz, qq);
      float dot = px * qx; dot = fmaf(py, qy, dot); dot = fmaf(pz, qz, dot);
      float d = 2.f * dot - pp - qq;
      top3_insert(d, m, d0, d1, d2, i0, i1, i2);
    }
    idx2[t * 3 + 0] = i0; idx2[t * 3 + 1] = i1; idx2[t * 3 + 2] = i2;
  }
  __syncthreads();

  // step 3: x2[o][kk] = max_nn F2(ofs = o*192 + kk*64 + nn)
  if (t < 18) {
    int o = t / 3, kk = t - o * 3;
    float mx = -INFINITY;
#pragma unroll 8
    for (int nn = 0; nn < 64; ++nn) {
      int ofs = o * 192 + kk * 64 + nn;
      int np = ofs / 18; int rem = ofs - np * 18;
      int kp = rem / 6;  int cp  = rem - kp * 6;
      float val = (cp < 3) ? (a1[idx2[np * 3 + kp] * 3 + cp] - a1[np * 3 + cp])
                           : a1[np * 3 + cp - 3];
      mx = fmaxf(mx, val);
    }
    a2[t] = mx;
  }
  __syncthreads();

  // steps 4-5: N=6 graph-feature twice (a2 -> a3 -> a4)
  for (int stage = 0; stage < 2; ++stage) {
    const float* src = (stage == 0) ? a2 : a3;
    float*       dst = (stage == 0) ? a3 : a4;
    if (t < 6) {
      float px = src[t], py = src[6 + t], pz = src[12 + t];
      float pp = px * px; pp = fmaf(py, py, pp); pp = fmaf(pz, pz, pp);
      float d0 = -INFINITY, d1 = -INFINITY, d2 = -INFINITY;
      int i0 = 0, i1 = 0, i2 = 0;
#pragma unroll
      for (int m = 0; m < 6; ++m) {
        float qx = src[m], qy = src[6 + m], qz = src[12 + m];
        float qq = qx * qx; qq = fmaf(qy, qy, qq); qq = fmaf(qz, qz, qq);
        float dot = px * qx; dot = fmaf(py, qy, dot); dot = fmaf(pz, qz, dot);
        float d = 2.f * dot - pp - qq;
        top3_insert(d, m, d0, d1, d2, i0, i1, i2);
      }
      idxs[t * 3 + 0] = i0; idxs[t * 3 + 1] = i1; idxs[t * 3 + 2] = i2;
    }
    __syncthreads();
    if (t < 18) {
      int o = t / 3, kk = t - o * 3;
      float mx = -INFINITY;
#pragma unroll
      for (int nn = 0; nn < 6; ++nn) {
        int ofs = o * 18 + kk * 6 + nn;
        int np = ofs / 18; int rem = ofs - np * 18;
        int kp = rem / 6;  int cp  = rem - kp * 6;
        float val = (cp < 3) ? (src[idxs[np * 3 + kp] * 3 + cp] - src[np * 3 + cp])
                             : src[np * 3 + cp - 3];
        mx = fmaxf(mx, val);
      }
      dst[t] = mx;
    }
    __syncthreads();
  }

  // step 6: p[82] = max over k
  if (t < 82) {
    float mx;
    if (t < 64)      { int o = t;      mx = fmaxf(fmaxf(a1[o*3], a1[o*3+1]), a1[o*3+2]); }
    else if (t < 70) { int o = t - 64; mx = fmaxf(fmaxf(a2[o*3], a2[o*3+1]), a2[o*3+2]); }
    else if (t < 76) { int o = t - 70; mx = fmaxf(fmaxf(a3[o*3], a3[o*3+1]), a3[o*3+2]); }
    else             { int o = t - 76; mx = fmaxf(fmaxf(a4[o*3], a4[o*3+1]), a4[o*3+2]); }
    pv[t] = mx;
  }
  __syncthreads();

  // step 7: hA = leaky(bnA(p @ wA.T + bA))  (256 outputs)
  {
    float acc = bA[t];
    const float* wr = wA + t * 82;
#pragma unroll 8
    for (int i = 0; i < 82; ++i) acc = fmaf(wr[i], pv[i], acc);
    float inv = bnAg[t] / sqrtf(bnAv[t] + EPSV);
    float v = (acc - bnAm[t]) * inv + bnAb[t];
    hA[t] = v >= 0.f ? v : 0.2f * v;
  }
  __syncthreads();

  // step 8: hB (128 outputs)
  if (t < 128) {
    float acc = bB[t];
    const float4* wr4 = (const float4*)(wB + t * 256);
#pragma unroll 8
    for (int i = 0; i < 64; ++i) {
      float4 wv = wr4[i];
      acc = fmaf(wv.x, hA[4 * i + 0], acc);
      acc = fmaf(wv.y, hA[4 * i + 1], acc);
      acc = fmaf(wv.z, hA[4 * i + 2], acc);
      acc = fmaf(wv.w, hA[4 * i + 3], acc);
    }
    float inv = bnBg[t] / sqrtf(bnBv[t] + EPSV);
    float v = (acc - bnBm[t]) * inv + bnBb[t];
    hB[t] = v >= 0.f ? v : 0.2f * v;
  }
  __syncthreads();

  // step 9: logits + softmax
  if (t < 3) {
    float acc = bC[t];
    const float* wr = wC + t * 128;
#pragma unroll 8
    for (int i = 0; i < 128; ++i) acc = fmaf(wr[i], hB[i], acc);
    lg[t] = acc;
  }
  __syncthreads();
  if (t == 0) {
    float m = fmaxf(fmaxf(lg[0], lg[1]), lg[2]);
    float e0 = expf(lg[0] - m), e1 = expf(lg[1] - m), e2 = expf(lg[2] - m);
    float s = e0 + e1 + e2;
    out[b * 3 + 0] = e0 / s;
    out[b * 3 + 1] = e1 / s;
    out[b * 3 + 2] = e2 / s;
  }
}

extern "C" void kernel_launch(void* const* d_in, const int* in_sizes, int n_in,
                              void* d_out, int out_size, void* d_ws, size_t ws_size,
                              hipStream_t stream) {
  (void)in_sizes; (void)n_in; (void)out_size; (void)ws_size;
  const float* x    = (const float*)d_in[0];
  const float* w1   = (const float*)d_in[1];
  const float* wA   = (const float*)d_in[2];
  const float* bA   = (const float*)d_in[3];
  const float* wB   = (const float*)d_in[4];
  const float* bB   = (const float*)d_in[5];
  const float* wC   = (const float*)d_in[6];
  const float* bC   = (const float*)d_in[7];
  const float* bn1g = (const float*)d_in[8];
  const float* bn1b = (const float*)d_in[9];
  const float* bn1m = (const float*)d_in[10];
  const float* bn1v = (const float*)d_in[11];
  const float* bnAg = (const float*)d_in[12];
  const float* bnAb = (const float*)d_in[13];
  const float* bnAm = (const float*)d_in[14];
  const float* bnAv = (const float*)d_in[15];
  const float* bnBg = (const float*)d_in[16];
  const float* bnBb = (const float*)d_in[17];
  const float* bnBm = (const float*)d_in[18];
  const float* bnBv = (const float*)d_in[19];
  float* out = (float*)d_out;

  int*   idx1 = (int*)d_ws;                                  // 8*4096*3 ints = 384 KB
  float* pmax = (float*)((char*)d_ws + 8 * 4096 * 3 * 4);    // 8*3*64*32 floats = 192 KB

  k_knn1<<<512, 512, 0, stream>>>(x, idx1);
  k_convmax<<<768, 256, 0, stream>>>(x, idx1, w1, pmax);
  k_tail<<<8, 256, 0, stream>>>(pmax,
                                bn1g, bn1b, bn1m, bn1v,
                                wA, bA, bnAg, bnAb, bnAm, bnAv,
                                wB, bB, bnBg, bnBb, bnBm, bnBv,
                                wC, bC, out);
}